// Round 3
// baseline (23291.844 us; speedup 1.0000x reference)
//
#include <hip/hip_runtime.h>

typedef unsigned short u16;
typedef unsigned int u32;

#define NT 512
#define Bv 32
#define Tv 256
#define Wv 128
#define Rv 4
#define Nv 128
#define G4 512
#define INSZv 640
#define IFJ 920
#define DELTAv 1e-6f

__device__ __forceinline__ float bf2f(u16 u){
  union { u32 i; float f; } c; c.i = ((u32)u) << 16; return c.f;
}
__device__ __forceinline__ u16 f2bf(float f){
  union { float f; u32 u; } c; c.f = f;
  u32 u = c.u;
  return (u16)((u + 0x7fffu + ((u >> 16) & 1u)) >> 16);
}
__device__ __forceinline__ float sigm(float x){ return 1.0f / (1.0f + __expf(-x)); }
__device__ __forceinline__ float softplusf(float x){ return fmaxf(x, 0.f) + log1pf(__expf(-fabsf(x))); }
__device__ __forceinline__ float wredsum(float v){
  #pragma unroll
  for (int o = 32; o > 0; o >>= 1) v += __shfl_down(v, o, 64);
  return v;
}
__device__ __forceinline__ float wredmax(float v){
  #pragma unroll
  for (int o = 32; o > 0; o >>= 1) v = fmaxf(v, __shfl_down(v, o, 64));
  return v;
}

// ---- dtype detection: flag[0] = 1 if input buffer is float32, 0 if bf16 ----
// fp32 data read as u16 pairs: even halfwords are low-mantissa bits -> bf16
// patterns with wild exponents. bf16 N(0,1) data: exponents near 127.
__global__ void detect_dtype(const u16* __restrict__ buf, int* __restrict__ flag){
  int lane = threadIdx.x;  // 64 threads
  float crazy = 0.f;
  for (int i = 0; i < 4; i++){
    u16 v = buf[lane * 4 + i];
    int e = (v >> 7) & 0xFF;
    if (e != 0 && (e < 117 || e > 137)) crazy += 1.f;
  }
  crazy = wredsum(crazy);
  if (lane == 0) flag[0] = (crazy >= 32.f) ? 1 : 0;
}

// Pack W[j,k] ([Js x K], bf16 or fp32 per flag) into float2 pairs:
// dst[(k/2)*Jd + j] = { W[j,2k2], W[j,2k2+1] } as fp32 (exact either way).
__global__ void pack_w2(const void* __restrict__ src, float2* __restrict__ dst,
                        int Js, int Jd, int K, const int* __restrict__ flag){
  int j = blockIdx.x * 256 + threadIdx.x;
  int k2 = blockIdx.y;
  if (j >= Jd) return;
  float2 o = make_float2(0.f, 0.f);
  if (j < Js){
    if (flag[0]){
      const float* s = (const float*)src;
      o.x = s[(size_t)j * K + 2 * k2];
      o.y = s[(size_t)j * K + 2 * k2 + 1];
    } else {
      const u16* s = (const u16*)src;
      o.x = bf2f(s[(size_t)j * K + 2 * k2]);
      o.y = bf2f(s[(size_t)j * K + 2 * k2 + 1]);
    }
  }
  dst[(size_t)k2 * Jd + j] = o;
}

__global__ void zero_f2(float2* __restrict__ p, int n){
  int i = blockIdx.x * 256 + threadIdx.x;
  if (i < n) p[i] = make_float2(0.f, 0.f);
}

// Diagnostic fallback: distinguishable finite output if workspace too small.
__global__ void fill_half(u16* __restrict__ p, int n){
  int i = blockIdx.x * 256 + threadIdx.x;
  if (i < n) p[i] = 0x3F00;  // bf16 0.5 (fp32 view ~0.5004 too)
}

__device__ __forceinline__ float ldval(const void* p, int idx, int dt32){
  return dt32 ? ((const float*)p)[idx] : bf2f(((const u16*)p)[idx]);
}

__global__ __launch_bounds__(NT) void dnc_main(
    const void* __restrict__ input,
    const void* __restrict__ enc_bih_g, const void* __restrict__ enc_bhh_g,
    const void* __restrict__ ctl_bih_g, const void* __restrict__ ctl_bhh_g,
    const void* __restrict__ iface_b_g, const void* __restrict__ out_b_g,
    const float2* __restrict__ encPWih, const float2* __restrict__ encPWhh,
    const float2* __restrict__ ctlPWih, const float2* __restrict__ ctlPWhh,
    const float2* __restrict__ ifPW, const float2* __restrict__ outPW,
    float* __restrict__ memG, float* __restrict__ linkG,
    void* __restrict__ outp, const int* __restrict__ dtflag)
{
  const int b = blockIdx.x;
  const int tid = threadIdx.x;
  const int lane = tid & 63;
  const int wid = tid >> 6;
  const int dt32 = dtflag[0];

  __shared__ __align__(16) float xbuf[INSZv];
  __shared__ __align__(16) float hES[Wv];
  __shared__ __align__(16) float cES[Wv];
  __shared__ __align__(16) float hS[Wv];
  __shared__ __align__(16) float cS[Wv];
  __shared__ __align__(16) float gS[G4];
  __shared__ __align__(16) float xiS[IFJ];
  __shared__ __align__(16) float rvS[Rv][Wv];
  __shared__ __align__(16) float rwS[Rv][Nv];
  __shared__ __align__(16) float rkeyS[Rv][Wv];
  __shared__ __align__(16) float wkeyS[Wv];
  __shared__ __align__(16) float eraseS[Wv];
  __shared__ __align__(16) float wvecS[Wv];
  __shared__ __align__(16) float wwS[Nv];
  __shared__ __align__(16) float usageS[Nv];
  __shared__ __align__(16) float precS[Nv];
  __shared__ __align__(16) float wcS[Nv];
  __shared__ __align__(16) float rcS[Rv][Nv];
  __shared__ __align__(16) float fwS[Rv][Nv];
  __shared__ __align__(16) float bwS[Rv][Nv];
  __shared__ __align__(16) float uS[Nv];
  __shared__ __align__(16) float sortedU[Nv];
  __shared__ __align__(16) float scanA[Nv];
  __shared__ __align__(16) float encBias[G4];
  __shared__ __align__(16) float ctlBias[G4];
  __shared__ __align__(16) float ifBias[IFJ];
  __shared__ __align__(16) float outBias[Wv];
  __shared__ float rstrS[Rv], fgS[Rv], rmS[Rv][3], scal[8];

  // ---- preload biases, init recurrent state ----
  encBias[tid] = ldval(enc_bih_g, tid, dt32) + ldval(enc_bhh_g, tid, dt32);
  ctlBias[tid] = ldval(ctl_bih_g, tid, dt32) + ldval(ctl_bhh_g, tid, dt32);
  ifBias[tid] = (tid < 919) ? ldval(iface_b_g, tid, dt32) : 0.f;
  {
    int j = tid + 512;
    if (j < IFJ) ifBias[j] = (j < 919) ? ldval(iface_b_g, j, dt32) : 0.f;
  }
  if (tid < Wv){
    outBias[tid] = ldval(out_b_g, tid, dt32);
    hES[tid] = 0.f; cES[tid] = 0.f;
    hS[tid] = 0.f; cS[tid] = 0.f;
    usageS[tid] = 0.f; precS[tid] = 0.f; wwS[tid] = 0.f;
  }
  { int r = tid >> 7, w = tid & 127; rvS[r][w] = 0.f; rwS[r][w] = 0.f; }
  float* memB = memG + (size_t)b * Nv * Wv;
  float* linkB = linkG + (size_t)b * Nv * Nv;
  for (int i = tid; i < Nv * Wv; i += NT) memB[i] = 0.f;
  for (int i = tid; i < Nv * Nv; i += NT) linkB[i] = 0.f;
  __syncthreads();

  // =========================== fused encoder + DNC loop ===========================
  for (int t = 0; t < Tv; ++t){
    // E0: input_t
    if (tid < Wv){
      int idx = ((size_t)b * Tv + t) * Wv + tid;
      xbuf[tid] = dt32 ? ((const float*)input)[idx] : bf2f(((const u16*)input)[idx]);
    }
    __syncthreads();

    // E1: encoder gates
    {
      float acc0 = encBias[tid], acc1 = 0.f;
      #pragma unroll 4
      for (int k2 = 0; k2 < Wv / 2; k2++){
        float2 x2 = *(const float2*)(xbuf + 2 * k2);
        float2 h2 = *(const float2*)(hES + 2 * k2);
        float2 wa = encPWih[k2 * G4 + tid];
        float2 wb = encPWhh[k2 * G4 + tid];
        acc0 += x2.x * wa.x + h2.x * wb.x;
        acc1 += x2.y * wa.y + h2.y * wb.y;
      }
      gS[tid] = acc0 + acc1;
    }
    __syncthreads();

    // E2: encoder LSTM pointwise
    if (tid < Wv){
      float ig = sigm(gS[tid]), fg = sigm(gS[Wv + tid]);
      float gg = tanhf(gS[2 * Wv + tid]), og = sigm(gS[3 * Wv + tid]);
      float cn = fg * cES[tid] + ig * gg;
      float hn = og * tanhf(cn);
      cES[tid] = cn; hES[tid] = hn;
    }
    __syncthreads();

    // P0: controller x (interleaved)
    if (tid < Wv){
      xbuf[5 * tid] = hES[tid];
      xbuf[5 * tid + 1] = rvS[0][tid];
      xbuf[5 * tid + 2] = rvS[1][tid];
      xbuf[5 * tid + 3] = rvS[2][tid];
      xbuf[5 * tid + 4] = rvS[3][tid];
    }
    __syncthreads();

    // P1: controller gates
    {
      float acc0 = ctlBias[tid], acc1 = 0.f;
      #pragma unroll 4
      for (int k2 = 0; k2 < INSZv / 2; k2++){
        float2 x2 = *(const float2*)(xbuf + 2 * k2);
        float2 wa = ctlPWih[k2 * G4 + tid];
        acc0 += x2.x * wa.x; acc1 += x2.y * wa.y;
      }
      #pragma unroll 4
      for (int k2 = 0; k2 < Wv / 2; k2++){
        float2 h2 = *(const float2*)(hS + 2 * k2);
        float2 wa = ctlPWhh[k2 * G4 + tid];
        acc0 += h2.x * wa.x; acc1 += h2.y * wa.y;
      }
      gS[tid] = acc0 + acc1;
    }
    __syncthreads();

    // P2: controller LSTM pointwise
    if (tid < Wv){
      float ig = sigm(gS[tid]), fg = sigm(gS[Wv + tid]);
      float gg = tanhf(gS[2 * Wv + tid]), og = sigm(gS[3 * Wv + tid]);
      float cn = fg * cS[tid] + ig * gg;
      float hn = og * tanhf(cn);
      cS[tid] = cn; hS[tid] = hn;
    }
    __syncthreads();

    // P3: interface vector
    {
      float acc0 = ifBias[tid];
      float acc1 = (tid < 408) ? ifBias[512 + tid] : 0.f;
      #pragma unroll 4
      for (int k2 = 0; k2 < Wv / 2; k2++){
        float2 h2 = *(const float2*)(hS + 2 * k2);
        float2 wa = ifPW[k2 * IFJ + tid];
        acc0 += h2.x * wa.x + h2.y * wa.y;
        float2 wb = ifPW[k2 * IFJ + 512 + tid];  // pad region zeroed/finite
        acc1 += h2.x * wb.x + h2.y * wb.y;
      }
      xiS[tid] = acc0;
      if (tid < 408) xiS[512 + tid] = acc1;
    }
    __syncthreads();

    // parse interface
    { int r = tid >> 7, w = tid & 127; rkeyS[r][w] = tanhf(xiS[r * Wv + w]); }
    if (tid < Wv){
      wkeyS[tid] = tanhf(xiS[516 + tid]);
      eraseS[tid] = sigm(xiS[645 + tid]);
      wvecS[tid] = tanhf(xiS[773 + tid]);
    }
    if (tid < Rv){
      rstrS[tid] = softplusf(xiS[512 + tid]);
      fgS[tid] = sigm(xiS[901 + tid]);
      float m0 = xiS[907 + 3 * tid], m1 = xiS[908 + 3 * tid], m2 = xiS[909 + 3 * tid];
      float mx = fmaxf(m0, fmaxf(m1, m2));
      float e0 = __expf(m0 - mx), e1 = __expf(m1 - mx), e2 = __expf(m2 - mx);
      float s = e0 + e1 + e2;
      rmS[tid][0] = e0 / s; rmS[tid][1] = e1 / s; rmS[tid][2] = e2 / s;
    }
    if (tid == 0){
      scal[0] = softplusf(xiS[644]);  // write_str
      scal[1] = sigm(xiS[905]);       // alloc_gate
      scal[2] = sigm(xiS[906]);       // write_gate
    }
    __syncthreads();

    // normalize keys
    if (wid < 5){
      float* arr = (wid < 4) ? rkeyS[wid] : wkeyS;
      float a = arr[lane], bq = arr[lane + 64];
      float s = wredsum(a * a + bq * bq);
      s = __shfl(s, 0, 64);
      float inv = 1.0f / (sqrtf(s) + DELTAv);
      arr[lane] = a * inv; arr[lane + 64] = bq * inv;
    }
    __syncthreads();

    // P4: usage update (old ww, old rw)
    if (tid < Nv){
      float us = usageS[tid];
      us = us + (1.f - us) * wwS[tid];
      float ret = (1.f - fgS[0] * rwS[0][tid]) * (1.f - fgS[1] * rwS[1][tid]) *
                  (1.f - fgS[2] * rwS[2][tid]) * (1.f - fgS[3] * rwS[3][tid]);
      usageS[tid] = us * ret;
    }

    // P5: write content scores (old mem)
    if (tid < Nv){
      const float4* mr4 = (const float4*)(memB + tid * Wv);
      float sq = 0.f, dt = 0.f;
      #pragma unroll 8
      for (int q = 0; q < Wv / 4; q++){
        float4 m = mr4[q];
        float4 wk = *(const float4*)(wkeyS + 4 * q);
        sq += m.x * m.x + m.y * m.y + m.z * m.z + m.w * m.w;
        dt += m.x * wk.x + m.y * wk.y + m.z * wk.z + m.w * wk.w;
      }
      wcS[tid] = dt / (sqrtf(sq) + DELTAv) * scal[0];
    }
    __syncthreads();
    if (wid == 0){
      float a = wcS[lane], bq = wcS[lane + 64];
      float mx = wredmax(fmaxf(a, bq)); mx = __shfl(mx, 0, 64);
      float ea = __expf(a - mx), eb = __expf(bq - mx);
      float s = wredsum(ea + eb); s = __shfl(s, 0, 64);
      wcS[lane] = ea / s; wcS[lane + 64] = eb / s;
    }
    __syncthreads();

    // P6: allocation weighting
    if (tid < Nv) uS[tid] = DELTAv + (1.f - DELTAv) * usageS[tid];
    __syncthreads();
    int rnk = 0;
    if (tid < Nv){
      float un = uS[tid];
      int r = 0;
      for (int m = 0; m < Nv; m++){
        float um = uS[m];
        r += (um < un) || (um == un && m < tid);
      }
      rnk = r;
      sortedU[r] = un;
    }
    __syncthreads();
    if (tid < Nv) scanA[tid] = sortedU[tid];
    __syncthreads();
    for (int off = 1; off < Nv; off <<= 1){
      float tv = 1.f;
      if (tid < Nv && tid >= off) tv = scanA[tid - off];
      __syncthreads();
      if (tid < Nv && tid >= off) scanA[tid] *= tv;
      __syncthreads();
    }
    if (tid < Nv){
      float ex = (rnk == 0) ? 1.f : scanA[rnk - 1];
      float al = (1.f - uS[tid]) * ex;
      wwS[tid] = scal[2] * (scal[1] * al + (1.f - scal[1]) * wcS[tid]);
    }
    __syncthreads();
    if (wid == 0){
      float s = wredsum(wwS[lane] + wwS[lane + 64]);
      if (lane == 0) scal[3] = s;
    }
    __syncthreads();

    // P7+P8: mem erase/write + link update
    {
      float4* m4 = (float4*)memB;
      float4* l4 = (float4*)linkB;
      #pragma unroll
      for (int it = 0; it < (Nv * Wv / 4) / NT; it++){
        int e4 = it * NT + tid;
        int n = e4 >> 5;
        int w0 = (e4 & 31) * 4;
        float wwn = wwS[n];
        float4 m = m4[e4];
        m.x = m.x * (1.f - wwn * eraseS[w0 + 0]) + wwn * wvecS[w0 + 0];
        m.y = m.y * (1.f - wwn * eraseS[w0 + 1]) + wwn * wvecS[w0 + 1];
        m.z = m.z * (1.f - wwn * eraseS[w0 + 2]) + wwn * wvecS[w0 + 2];
        m.w = m.w * (1.f - wwn * eraseS[w0 + 3]) + wwn * wvecS[w0 + 3];
        m4[e4] = m;
        float4 l = l4[e4];
        l.x = (n == w0 + 0) ? 0.f : ((1.f - wwn - wwS[w0 + 0]) * l.x + wwn * precS[w0 + 0]);
        l.y = (n == w0 + 1) ? 0.f : ((1.f - wwn - wwS[w0 + 1]) * l.y + wwn * precS[w0 + 1]);
        l.z = (n == w0 + 2) ? 0.f : ((1.f - wwn - wwS[w0 + 2]) * l.z + wwn * precS[w0 + 2]);
        l.w = (n == w0 + 3) ? 0.f : ((1.f - wwn - wwS[w0 + 3]) * l.w + wwn * precS[w0 + 3]);
        l4[e4] = l;
      }
    }
    __syncthreads();
    if (tid < Nv) precS[tid] = (1.f - scal[3]) * precS[tid] + wwS[tid];

    // P9: read content scores (new mem)
    if (tid < Nv){
      const float4* mr4 = (const float4*)(memB + tid * Wv);
      float sq = 0.f, d0 = 0.f, d1 = 0.f, d2 = 0.f, d3 = 0.f;
      #pragma unroll 4
      for (int q = 0; q < Wv / 4; q++){
        float4 m = mr4[q];
        float4 k0 = *(const float4*)(&rkeyS[0][4 * q]);
        float4 k1 = *(const float4*)(&rkeyS[1][4 * q]);
        float4 k2 = *(const float4*)(&rkeyS[2][4 * q]);
        float4 k3 = *(const float4*)(&rkeyS[3][4 * q]);
        sq += m.x * m.x + m.y * m.y + m.z * m.z + m.w * m.w;
        d0 += m.x * k0.x + m.y * k0.y + m.z * k0.z + m.w * k0.w;
        d1 += m.x * k1.x + m.y * k1.y + m.z * k1.z + m.w * k1.w;
        d2 += m.x * k2.x + m.y * k2.y + m.z * k2.z + m.w * k2.w;
        d3 += m.x * k3.x + m.y * k3.y + m.z * k3.z + m.w * k3.w;
      }
      float inv = 1.f / (sqrtf(sq) + DELTAv);
      rcS[0][tid] = d0 * inv * rstrS[0];
      rcS[1][tid] = d1 * inv * rstrS[1];
      rcS[2][tid] = d2 * inv * rstrS[2];
      rcS[3][tid] = d3 * inv * rstrS[3];
    }
    __syncthreads();
    if (wid < 4){
      float a = rcS[wid][lane], bq = rcS[wid][lane + 64];
      float mx = wredmax(fmaxf(a, bq)); mx = __shfl(mx, 0, 64);
      float ea = __expf(a - mx), eb = __expf(bq - mx);
      float s = wredsum(ea + eb); s = __shfl(s, 0, 64);
      rcS[wid][lane] = ea / s; rcS[wid][lane + 64] = eb / s;
    }
    __syncthreads();

    // P10: fw/bw (new link, old rw)
    {
      int r = tid >> 7, i = tid & 127;
      const float4* lr4 = (const float4*)(linkB + i * Nv);
      float f = 0.f, bk = 0.f;
      #pragma unroll 4
      for (int q = 0; q < Nv / 4; q++){
        float4 lrow = lr4[q];
        float4 rwv = *(const float4*)(&rwS[r][4 * q]);
        f += lrow.x * rwv.x + lrow.y * rwv.y + lrow.z * rwv.z + lrow.w * rwv.w;
        int j = 4 * q;
        bk += rwv.x * linkB[(j + 0) * Nv + i] + rwv.y * linkB[(j + 1) * Nv + i]
            + rwv.z * linkB[(j + 2) * Nv + i] + rwv.w * linkB[(j + 3) * Nv + i];
      }
      fwS[r][i] = f; bwS[r][i] = bk;
    }
    __syncthreads();

    // P11: new read weights
    {
      int r = tid >> 7, n = tid & 127;
      float nv = rmS[r][0] * bwS[r][n] + rmS[r][1] * fwS[r][n] + rmS[r][2] * rcS[r][n];
      rwS[r][n] = nv;
    }
    __syncthreads();

    // P12: read vectors
    {
      int r = tid >> 7, w = tid & 127;
      float acc = 0.f;
      #pragma unroll 8
      for (int n = 0; n < Nv; n++) acc += rwS[r][n] * memB[n * Wv + w];
      rvS[r][w] = acc;
    }
    __syncthreads();

    // P13: output projection
    if (tid < Wv){
      xbuf[tid] = hS[tid];
      xbuf[Wv + 4 * tid + 0] = rvS[0][tid];
      xbuf[Wv + 4 * tid + 1] = rvS[1][tid];
      xbuf[Wv + 4 * tid + 2] = rvS[2][tid];
      xbuf[Wv + 4 * tid + 3] = rvS[3][tid];
    }
    __syncthreads();
    {
      int p = tid >> 7, j = tid & 127;
      float a0 = 0.f, a1 = 0.f;
      #pragma unroll 4
      for (int k2 = p * 80; k2 < p * 80 + 80; k2++){
        float2 x2 = *(const float2*)(xbuf + 2 * k2);
        float2 w2 = outPW[k2 * Wv + j];
        a0 += x2.x * w2.x; a1 += x2.y * w2.y;
      }
      gS[tid] = a0 + a1;
    }
    __syncthreads();
    if (tid < Wv){
      float o = outBias[tid] + gS[tid] + gS[Wv + tid] + gS[2 * Wv + tid] + gS[3 * Wv + tid];
      size_t oi = ((size_t)b * Tv + t) * Wv + tid;
      if (dt32) ((float*)outp)[oi] = o;
      else ((u16*)outp)[oi] = f2bf(o);
    }
    __syncthreads();
  }
}

extern "C" void kernel_launch(void* const* d_in, const int* in_sizes, int n_in,
                              void* d_out, int out_size, void* d_ws, size_t ws_size,
                              hipStream_t stream) {
  (void)in_sizes; (void)n_in;
  const void* input   = d_in[0];
  // d_in[1] = source_lengths (int32, all == T) — unused
  const void* enc_Wih = d_in[2];
  const void* enc_Whh = d_in[3];
  const void* enc_bih = d_in[4];
  const void* enc_bhh = d_in[5];
  const void* ctl_Wih = d_in[6];
  const void* ctl_Whh = d_in[7];
  const void* ctl_bih = d_in[8];
  const void* ctl_bhh = d_in[9];
  const void* iface_W = d_in[10];
  const void* iface_b = d_in[11];
  const void* out_W   = d_in[12];
  const void* out_b   = d_in[13];

  // workspace layout (bytes)
  char* ws = (char*)d_ws;
  size_t off = 0;
  int* dtflag = (int*)(ws + off); off += 16;
  float2* encPWih = (float2*)(ws + off); off += (size_t)64 * 512 * 8;
  float2* encPWhh = (float2*)(ws + off); off += (size_t)64 * 512 * 8;
  float2* ctlPWih = (float2*)(ws + off); off += (size_t)320 * 512 * 8;
  float2* ctlPWhh = (float2*)(ws + off); off += (size_t)64 * 512 * 8;
  float2* ifPW    = (float2*)(ws + off); off += (size_t)(64 * 920 + 256) * 8;
  float2* outPW   = (float2*)(ws + off); off += (size_t)320 * 128 * 8;
  float* memG  = (float*)(ws + off); off += (size_t)Bv * Nv * Wv * 4;
  float* linkG = (float*)(ws + off); off += (size_t)Bv * Nv * Nv * 4;
  const size_t need_bytes = off;  // ~7.1 MB

  if (ws_size < need_bytes){
    fill_half<<<dim3((out_size + 255) / 256), dim3(256), 0, stream>>>((u16*)d_out, out_size);
    return;
  }

  detect_dtype<<<dim3(1), dim3(64), 0, stream>>>((const u16*)input, dtflag);

  pack_w2<<<dim3(2, 64), 256, 0, stream>>>(enc_Wih, encPWih, 512, 512, 128, dtflag);
  pack_w2<<<dim3(2, 64), 256, 0, stream>>>(enc_Whh, encPWhh, 512, 512, 128, dtflag);
  pack_w2<<<dim3(2, 320), 256, 0, stream>>>(ctl_Wih, ctlPWih, 512, 512, 640, dtflag);
  pack_w2<<<dim3(2, 64), 256, 0, stream>>>(ctl_Whh, ctlPWhh, 512, 512, 128, dtflag);
  pack_w2<<<dim3(4, 64), 256, 0, stream>>>(iface_W, ifPW, 919, 920, 128, dtflag);
  zero_f2<<<dim3(1), dim3(256), 0, stream>>>(ifPW + 64 * 920, 256);
  pack_w2<<<dim3(1, 320), 256, 0, stream>>>(out_W, outPW, 128, 128, 640, dtflag);

  dnc_main<<<dim3(Bv), dim3(NT), 0, stream>>>(
      input, enc_bih, enc_bhh, ctl_bih, ctl_bhh, iface_b, out_b,
      encPWih, encPWhh, ctlPWih, ctlPWhh, ifPW, outPW,
      memG, linkG, d_out, dtflag);
}